// Round 1
// baseline (217.250 us; speedup 1.0000x reference)
//
#include <hip/hip_runtime.h>
#include <math.h>

#define B  128
#define NV 4096
#define NE 262144

// ---------------------------------------------------------------------------
// k_prep: read x,error [B,N] row-major; write T_t = tanh(x) and err_t in
// node-major [N,B] layout via LDS 32x32 tile transpose (padded, conflict-free).
// ---------------------------------------------------------------------------
__global__ void k_prep(const float* __restrict__ x, const float* __restrict__ err,
                       float* __restrict__ T_t, float* __restrict__ err_t) {
    __shared__ float tx[32][33];
    __shared__ float te[32][33];
    int n0 = blockIdx.x * 32;   // node tile
    int b0 = blockIdx.y * 32;   // batch tile
    int a = threadIdx.x;        // fast dim
    int c = threadIdx.y;
    int gi = (b0 + c) * NV + (n0 + a);     // coalesced read over a
    tx[c][a] = tanhf(x[gi]);
    te[c][a] = err[gi];
    __syncthreads();
    int go = (n0 + c) * B + (b0 + a);      // coalesced write over a
    T_t[go]   = tx[a][c];
    err_t[go] = te[a][c];
}

// zero the 2*NV histogram counters
__global__ void k_zero(int* __restrict__ cnt) {
    int i = blockIdx.x * 256 + threadIdx.x;
    if (i < 2 * NV) cnt[i] = 0;
}

// histogram of edge endpoints: cnt[0..NV) by src, cnt[NV..2NV) by tgt
__global__ void k_hist(const int* __restrict__ ei, int* __restrict__ cnt) {
    int e = blockIdx.x * 256 + threadIdx.x;
    if (e < NE) {
        atomicAdd(&cnt[ei[e]], 1);            // src
        atomicAdd(&cnt[NV + ei[NE + e]], 1);  // tgt
    }
}

// exclusive scan of one NV-counter array per block (blockIdx.x in {0,1}).
// writes ofs[NV+1] and initializes cursor copy.
__global__ __launch_bounds__(1024) void k_scan(const int* __restrict__ cnt,
                                               int* __restrict__ ofs,
                                               int* __restrict__ cur) {
    int which = blockIdx.x;
    const int* c = cnt + which * NV;
    int* o  = ofs + which * (NV + 1);
    int* cu = cur + which * NV;
    __shared__ int s[1024];
    int t = threadIdx.x;
    int base = t * 4;
    int v[4], sum = 0;
#pragma unroll
    for (int i = 0; i < 4; ++i) { v[i] = c[base + i]; sum += v[i]; }
    s[t] = sum;
    __syncthreads();
    // Hillis-Steele inclusive scan over 1024 partials
    for (int off = 1; off < 1024; off <<= 1) {
        int add = (t >= off) ? s[t - off] : 0;
        __syncthreads();
        s[t] += add;
        __syncthreads();
    }
    int run = s[t] - sum;   // exclusive prefix
#pragma unroll
    for (int i = 0; i < 4; ++i) { o[base + i] = run; cu[base + i] = run; run += v[i]; }
    if (t == 1023) o[NV] = run;   // == NE
}

// scatter edges into src-sorted and tgt-sorted buckets; gather w_e once here.
__global__ void k_scatter(const int* __restrict__ ei, const float* __restrict__ w,
                          int* __restrict__ cur,
                          float* __restrict__ es_w, int* __restrict__ es_tgt,
                          float* __restrict__ et_w, int* __restrict__ et_src) {
    int e = blockIdx.x * 256 + threadIdx.x;
    if (e >= NE) return;
    int s = ei[e];
    int t = ei[NE + e];
    float we = w[s * NV + t];
    int p = atomicAdd(&cur[s], 1);
    es_w[p] = we; es_tgt[p] = t;
    int q = atomicAdd(&cur[NV + t], 1);
    et_w[q] = we; et_src[q] = s;
}

// mu[b, s] = sum over edges in src-bucket s of T[b, tgt_e] * w_e
// one block per src node, lane = batch. Edge metadata is wave-uniform -> s_load.
__global__ __launch_bounds__(128) void k_mu(const int* __restrict__ ofs,
                                            const float* __restrict__ es_w,
                                            const int* __restrict__ es_tgt,
                                            const float* __restrict__ T_t,
                                            float* __restrict__ mu_t) {
    int s = blockIdx.x;
    int b = threadIdx.x;
    int e0 = ofs[s], e1 = ofs[s + 1];
    float acc = 0.f;
    for (int e = e0; e < e1; ++e) {
        int   tg = es_tgt[e];
        float we = es_w[e];
        acc += T_t[tg * B + b] * we;
    }
    mu_t[s * B + b] = acc;
}

// aggr[b, t] = (1 - T[b,t]^2) * sum over edges in tgt-bucket t of err[b, src_e] * w_e
// dEdx = err - aggr, stored node-major.
__global__ __launch_bounds__(128) void k_grad(const int* __restrict__ ofs,
                                              const float* __restrict__ et_w,
                                              const int* __restrict__ et_src,
                                              const float* __restrict__ T_t,
                                              const float* __restrict__ err_t,
                                              float* __restrict__ dE_t) {
    int t = blockIdx.x;
    int b = threadIdx.x;
    int e0 = ofs[t], e1 = ofs[t + 1];
    float acc = 0.f;
    for (int e = e0; e < e1; ++e) {
        int   sr = et_src[e];
        float we = et_w[e];
        acc += err_t[sr * B + b] * we;
    }
    float th = T_t[t * B + b];
    dE_t[t * B + b] = err_t[t * B + b] - (1.f - th * th) * acc;
}

// transpose both node-major results back to [B,N] and write concatenated out.
__global__ void k_out(const float* __restrict__ mu_t, const float* __restrict__ dE_t,
                      float* __restrict__ out) {
    __shared__ float t0[32][33];
    __shared__ float t1[32][33];
    int n0 = blockIdx.x * 32;
    int b0 = blockIdx.y * 32;
    int a = threadIdx.x;
    int c = threadIdx.y;
    int gi = (n0 + c) * B + (b0 + a);      // coalesced over a (B fast)
    t0[c][a] = mu_t[gi];
    t1[c][a] = dE_t[gi];
    __syncthreads();
    int go = (b0 + c) * NV + (n0 + a);     // coalesced over a (N fast)
    out[go]          = t0[a][c];
    out[B * NV + go] = t1[a][c];
}

extern "C" void kernel_launch(void* const* d_in, const int* in_sizes, int n_in,
                              void* d_out, int out_size, void* d_ws, size_t ws_size,
                              hipStream_t stream) {
    const float* x   = (const float*)d_in[0];
    const float* err = (const float*)d_in[1];
    const float* w   = (const float*)d_in[2];
    const int*   ei  = (const int*)d_in[3];
    float* out = (float*)d_out;

    // workspace layout
    const int NB = NV * B;               // 524288
    float* T_t   = (float*)d_ws;
    float* err_t = T_t   + NB;
    float* mu_t  = err_t + NB;
    float* dE_t  = mu_t  + NB;
    int*   cnt   = (int*)(dE_t + NB);    // 2*NV
    int*   ofs   = cnt + 2 * NV;         // 2*(NV+1)
    int*   cur   = ofs + 2 * (NV + 1);   // 2*NV
    float* es_w  = (float*)(cur + 2 * NV);
    int*   es_tg = (int*)(es_w + NE);
    float* et_w  = (float*)(es_tg + NE);
    int*   et_sr = (int*)(et_w + NE);
    // total ~12.1 MB

    dim3 tb32(32, 32);
    dim3 tgrid(NV / 32, B / 32);

    k_prep<<<tgrid, tb32, 0, stream>>>(x, err, T_t, err_t);
    k_zero<<<(2 * NV + 255) / 256, 256, 0, stream>>>(cnt);
    k_hist<<<NE / 256, 256, 0, stream>>>(ei, cnt);
    k_scan<<<2, 1024, 0, stream>>>(cnt, ofs, cur);
    k_scatter<<<NE / 256, 256, 0, stream>>>(ei, w, cur, es_w, es_tg, et_w, et_sr);
    k_mu<<<NV, 128, 0, stream>>>(ofs, es_w, es_tg, T_t, mu_t);
    k_grad<<<NV, 128, 0, stream>>>(ofs + (NV + 1), et_w, et_sr, T_t, err_t, dE_t);
    k_out<<<tgrid, tb32, 0, stream>>>(mu_t, dE_t, out);
}

// Round 2
// 190.688 us; speedup vs baseline: 1.1393x; 1.1393x over previous
//
#include <hip/hip_runtime.h>
#include <math.h>

#define B  128
#define NV 4096
#define NE 262144

// ---------------------------------------------------------------------------
// k_prep: read x,error [B,N] row-major; write T_t = tanh(x) and err_t in
// node-major [N,B] layout via LDS 32x32 tile transpose (padded, conflict-free).
// ---------------------------------------------------------------------------
__global__ void k_prep(const float* __restrict__ x, const float* __restrict__ err,
                       float* __restrict__ T_t, float* __restrict__ err_t) {
    __shared__ float tx[32][33];
    __shared__ float te[32][33];
    int n0 = blockIdx.x * 32;   // node tile
    int b0 = blockIdx.y * 32;   // batch tile
    int a = threadIdx.x;        // fast dim
    int c = threadIdx.y;
    int gi = (b0 + c) * NV + (n0 + a);     // coalesced read over a
    tx[c][a] = tanhf(x[gi]);
    te[c][a] = err[gi];
    __syncthreads();
    int go = (n0 + c) * B + (b0 + a);      // coalesced write over a
    T_t[go]   = tx[a][c];
    err_t[go] = te[a][c];
}

// histogram of edge endpoints: cnt[0..NV) by src, cnt[NV..2NV) by tgt
__global__ void k_hist(const int* __restrict__ ei, int* __restrict__ cnt) {
    int e = blockIdx.x * 256 + threadIdx.x;
    if (e < NE) {
        atomicAdd(&cnt[ei[e]], 1);            // src
        atomicAdd(&cnt[NV + ei[NE + e]], 1);  // tgt
    }
}

// exclusive scan of one NV-counter array per block (blockIdx.x in {0,1}).
// writes ofs[NV+1] and initializes cursor copy.
__global__ __launch_bounds__(1024) void k_scan(const int* __restrict__ cnt,
                                               int* __restrict__ ofs,
                                               int* __restrict__ cur) {
    int which = blockIdx.x;
    const int* c = cnt + which * NV;
    int* o  = ofs + which * (NV + 1);
    int* cu = cur + which * NV;
    __shared__ int s[1024];
    int t = threadIdx.x;
    int base = t * 4;
    int v[4], sum = 0;
#pragma unroll
    for (int i = 0; i < 4; ++i) { v[i] = c[base + i]; sum += v[i]; }
    s[t] = sum;
    __syncthreads();
    for (int off = 1; off < 1024; off <<= 1) {
        int add = (t >= off) ? s[t - off] : 0;
        __syncthreads();
        s[t] += add;
        __syncthreads();
    }
    int run = s[t] - sum;   // exclusive prefix
#pragma unroll
    for (int i = 0; i < 4; ++i) { o[base + i] = run; cu[base + i] = run; run += v[i]; }
    if (t == 1023) o[NV] = run;   // == NE
}

// scatter edges into src-sorted and tgt-sorted buckets; gather w_e once here.
// payload packed as int2 {other_node, float_bits(w_e)} -> one 8B store per side.
__global__ void k_scatter(const int* __restrict__ ei, const float* __restrict__ w,
                          int* __restrict__ cur,
                          int2* __restrict__ es, int2* __restrict__ et) {
    int e = blockIdx.x * 256 + threadIdx.x;
    if (e >= NE) return;
    int s = ei[e];
    int t = ei[NE + e];
    int wb = __float_as_int(w[s * NV + t]);
    int p = atomicAdd(&cur[s], 1);
    es[p] = make_int2(t, wb);
    int q = atomicAdd(&cur[NV + t], 1);
    et[q] = make_int2(s, wb);
}

// Merged gather-reduce. blockIdx.x in [0, 2*NV):
//   [0, NV):   mu[b, s]  = sum_{e in src-bucket s} T[b, tgt_e] * w_e
//   [NV, 2NV): dEdx[b,t] = err[b,t] - (1 - T[b,t]^2) * sum_{e in tgt-bucket t} err[b, src_e] * w_e
// 64 threads (1 wave); each lane handles 2 batches via float2.
__global__ __launch_bounds__(64) void k_proc(const int* __restrict__ ofs,
                                             const int2* __restrict__ es,
                                             const int2* __restrict__ et,
                                             const float* __restrict__ T_t,
                                             const float* __restrict__ err_t,
                                             float* __restrict__ mu_t,
                                             float* __restrict__ dE_t) {
    int id = blockIdx.x;
    bool is_mu = id < NV;
    int node = is_mu ? id : id - NV;
    const int* o = is_mu ? ofs : (ofs + NV + 1);
    const int2* ed = is_mu ? es : et;
    const float2* src2 = (const float2*)(is_mu ? T_t : err_t);

    int e0 = o[node], e1 = o[node + 1];
    int lane = threadIdx.x;

    float2 a0 = make_float2(0.f, 0.f), a1 = make_float2(0.f, 0.f);
    float2 a2 = make_float2(0.f, 0.f), a3 = make_float2(0.f, 0.f);
    int e = e0;
    for (; e + 4 <= e1; e += 4) {
        int2 m0 = ed[e], m1 = ed[e + 1], m2 = ed[e + 2], m3 = ed[e + 3];
        float2 t0 = src2[m0.x * (B / 2) + lane];
        float2 t1 = src2[m1.x * (B / 2) + lane];
        float2 t2 = src2[m2.x * (B / 2) + lane];
        float2 t3 = src2[m3.x * (B / 2) + lane];
        float w0 = __int_as_float(m0.y), w1 = __int_as_float(m1.y);
        float w2 = __int_as_float(m2.y), w3 = __int_as_float(m3.y);
        a0.x += t0.x * w0; a0.y += t0.y * w0;
        a1.x += t1.x * w1; a1.y += t1.y * w1;
        a2.x += t2.x * w2; a2.y += t2.y * w2;
        a3.x += t3.x * w3; a3.y += t3.y * w3;
    }
    for (; e < e1; ++e) {
        int2 m = ed[e];
        float2 t = src2[m.x * (B / 2) + lane];
        float wv = __int_as_float(m.y);
        a0.x += t.x * wv; a0.y += t.y * wv;
    }
    float2 acc = make_float2(a0.x + a1.x + a2.x + a3.x,
                             a0.y + a1.y + a2.y + a3.y);

    int out_i = node * (B / 2) + lane;
    if (is_mu) {
        ((float2*)mu_t)[out_i] = acc;
    } else {
        float2 th = ((const float2*)T_t)[out_i];
        float2 er = ((const float2*)err_t)[out_i];
        float2 r;
        r.x = er.x - (1.f - th.x * th.x) * acc.x;
        r.y = er.y - (1.f - th.y * th.y) * acc.y;
        ((float2*)dE_t)[out_i] = r;
    }
}

// transpose both node-major results back to [B,N] and write concatenated out.
__global__ void k_out(const float* __restrict__ mu_t, const float* __restrict__ dE_t,
                      float* __restrict__ out) {
    __shared__ float t0[32][33];
    __shared__ float t1[32][33];
    int n0 = blockIdx.x * 32;
    int b0 = blockIdx.y * 32;
    int a = threadIdx.x;
    int c = threadIdx.y;
    int gi = (n0 + c) * B + (b0 + a);      // coalesced over a (B fast)
    t0[c][a] = mu_t[gi];
    t1[c][a] = dE_t[gi];
    __syncthreads();
    int go = (b0 + c) * NV + (n0 + a);     // coalesced over a (N fast)
    out[go]          = t0[a][c];
    out[B * NV + go] = t1[a][c];
}

extern "C" void kernel_launch(void* const* d_in, const int* in_sizes, int n_in,
                              void* d_out, int out_size, void* d_ws, size_t ws_size,
                              hipStream_t stream) {
    const float* x   = (const float*)d_in[0];
    const float* err = (const float*)d_in[1];
    const float* w   = (const float*)d_in[2];
    const int*   ei  = (const int*)d_in[3];
    float* out = (float*)d_out;

    // workspace layout
    const int NB = NV * B;               // 524288
    float* T_t   = (float*)d_ws;
    float* err_t = T_t   + NB;
    float* mu_t  = err_t + NB;
    float* dE_t  = mu_t  + NB;
    int*   cnt   = (int*)(dE_t + NB);    // 2*NV
    int*   ofs   = cnt + 2 * NV;         // 2*(NV+1)
    int*   cur   = ofs + 2 * (NV + 1);   // 2*NV
    int2*  es    = (int2*)(cur + 2 * NV);
    int2*  et    = es + NE;
    // total ~12 MB

    dim3 tb32(32, 32);
    dim3 tgrid(NV / 32, B / 32);

    k_prep<<<tgrid, tb32, 0, stream>>>(x, err, T_t, err_t);
    hipMemsetAsync(cnt, 0, 2 * NV * sizeof(int), stream);
    k_hist<<<NE / 256, 256, 0, stream>>>(ei, cnt);
    k_scan<<<2, 1024, 0, stream>>>(cnt, ofs, cur);
    k_scatter<<<NE / 256, 256, 0, stream>>>(ei, w, cur, es, et);
    k_proc<<<2 * NV, 64, 0, stream>>>(ofs, es, et, T_t, err_t, mu_t, dE_t);
    k_out<<<tgrid, tb32, 0, stream>>>(mu_t, dE_t, out);
}